// Round 4
// baseline (67.169 us; speedup 1.0000x reference)
//
#include <hip/hip_runtime.h>
#include <hip/hip_bf16.h>

// B=8, Lq=2048, Lk=2048, D=256. out = softmax(mask? sq_i+sk_j : -1e9) @ V.
// sq cancels in softmax => out[i] = (mask[i]·(e*V)) / (mask[i]·e), e=exp(K·w).
// Stage 1: e_bf16 + evT (bf16, transposed K-major). Stage 2: counted-vmcnt
// 3-buffer pipelined MFMA GEMM (T3/T4): loads go 2 K-steps ahead; the barrier
// waits s_waitcnt vmcnt(3) (this step's 3 VMEM ops stay in flight), never 0.
// BM=32/BK=32 -> 58KB LDS -> 2 blocks/CU (16 waves/CU, two independent
// barrier groups). Swizzle: chunk' = c ^ ((row>>1)&3) -> 2-way (free) b128.
// Workspace: evT 8*256*2048*2 = 8 MB, e_bf16 8*2048*2 = 32 KB.

#define NB 8
#define LQ 2048
#define LK 2048
#define DD 256
#define BK 32

typedef __attribute__((ext_vector_type(8))) short short8v;
typedef __attribute__((ext_vector_type(8))) unsigned short ushort8v;
typedef __attribute__((ext_vector_type(4))) float f32x4;

__device__ inline unsigned short f2bf(float x) {
  union { __hip_bfloat16 h; unsigned short u; } cv;
  cv.h = __float2bfloat16(x);
  return cv.u;
}

__device__ inline void gld_lds16(const unsigned short* g, unsigned short* l) {
  __builtin_amdgcn_global_load_lds(
      (const __attribute__((address_space(1))) void*)g,
      (__attribute__((address_space(3))) void*)l, 16, 0, 0);
}

// ---------------- Stage 1: e = exp(K·w) (bf16); evT[b][d][j] = bf16(e_j*V[j][d]) --
__global__ __launch_bounds__(256) void bah_precompute(
    const float* __restrict__ key, const float* __restrict__ value,
    const float* __restrict__ w, unsigned short* __restrict__ evT,
    unsigned short* __restrict__ eb)
{
  __shared__ float w_s[DD];
  __shared__ unsigned short t_s[64][DD];

  const int t = threadIdx.x;
  const int lane = t & 63;
  const int wid = t >> 6;
  const int blk = blockIdx.x;
  const int b = blk & 7;
  const int j0 = (blk >> 3) * 64;

  w_s[t] = w[t];
  __syncthreads();
  const float4 wv4 = reinterpret_cast<const float4*>(w_s)[lane];

  for (int it = 0; it < 16; ++it) {
    const int r = it * 4 + wid;
    const size_t row = (size_t)b * LK + (j0 + r);
    const float4 kv = reinterpret_cast<const float4*>(key + row * DD)[lane];
    float s = kv.x * wv4.x + kv.y * wv4.y + kv.z * wv4.z + kv.w * wv4.w;
#pragma unroll
    for (int off = 32; off; off >>= 1) s += __shfl_xor(s, off);
    const float e = __expf(s);
    if (lane == 0) eb[row] = f2bf(e);
    const float4 vv = reinterpret_cast<const float4*>(value + row * DD)[lane];
    ushort4 u;
    u.x = f2bf(e * vv.x);
    u.y = f2bf(e * vv.y);
    u.z = f2bf(e * vv.z);
    u.w = f2bf(e * vv.w);
    *reinterpret_cast<ushort4*>(&t_s[r][lane * 4]) = u;
  }
  __syncthreads();

  const int d = t;
  unsigned short* dst = evT + ((size_t)b * DD + d) * LK + j0;
#pragma unroll
  for (int s8 = 0; s8 < 8; ++s8) {
    ushort8v val;
#pragma unroll
    for (int c = 0; c < 8; ++c) val[c] = t_s[s8 * 8 + c][d];
    *reinterpret_cast<ushort8v*>(dst + s8 * 8) = val;
  }
}

// ---------------- Stage 2: counted-vmcnt pipelined masked GEMM ----------------
// BM=32, BN=256, BK=32, 512 thr (8 waves, 2m x 4n), wave tile 16x64.
// grid = 8 batches x 64 i-blocks = 512 -> 2 blocks/CU. blk&7 = batch = XCD.
__global__ __launch_bounds__(512, 4) void bah_gemm(
    const int* __restrict__ mask, const unsigned short* __restrict__ evT,
    const unsigned short* __restrict__ eb, float* __restrict__ out)
{
  __shared__ unsigned short A_s[3][32 * BK];    // 6 KB
  __shared__ unsigned short B_s[3][DD * BK];    // 48 KB
  __shared__ unsigned short e_s[LK];            // 4 KB
  __shared__ float denom_s[32];

  const int t = threadIdx.x;
  const int lane = t & 63;
  const int wid = t >> 6;
  const int wm = wid >> 2;                  // 0..1 (row half)
  const int wn = wid & 3;                   // 0..3 (d quarter)
  const int lr = lane & 15;
  const int kq = lane >> 4;                 // k quarter (8 ushorts each)

  const int blk = blockIdx.x;
  const int b = blk & 7;                    // batch -> XCD (evT L2-resident)
  const int i0 = (blk >> 3) * 32;

  // A staging: thread t -> row ar (16 thr/row), 2 ints at ac
  const int ar = t >> 4;                    // 0..31
  const int ac = (t & 15) * 2;              // 0..30
  const int aslot = ar * BK + (((ac >> 3) ^ ((ar >> 1) & 3)) * 8) + (ac & 7);
  const int* aptr = mask + ((size_t)b * LQ + i0 + ar) * LK + ac;

  // B staging: wave wid -> d rows [wid*32, wid*32+32), 2 gld_lds (16 rows each)
  const unsigned short* evTb = evT + (size_t)b * DD * LK;
  const int brow_in = lane >> 2;                         // 0..15 within window
  const int bsrc_off = ((lane & 3) ^ ((lane >> 3) & 3)) * 8;  // pre-swizzled chunk

  // e_s fill: 512 thr x 4 ushorts
  *reinterpret_cast<ushort4*>(&e_s[t * 4]) =
      *reinterpret_cast<const ushort4*>(eb + (size_t)b * LK + t * 4);

  // frag-read offsets (ushort indices)
  const int arow = wm * 16 + lr;
  const int aoff = arow * BK + ((kq ^ ((arow >> 1) & 3)) * 8);
  int boff[4];
#pragma unroll
  for (int n = 0; n < 4; ++n) {
    const int d = wn * 64 + n * 16 + lr;
    boff[n] = d * BK + ((kq ^ ((d >> 1) & 3)) * 8);
  }

  // ---- prologue: stage tiles 0 and 1 ----
  {
    const int2 a0 = *reinterpret_cast<const int2*>(aptr);           // A(0)
#pragma unroll
    for (int g = 0; g < 2; ++g)
      gld_lds16(evTb + (size_t)(wid * 32 + g * 16 + brow_in) * LK + bsrc_off,
                &B_s[0][(wid * 32 + g * 16) * BK]);                 // B(0)
    const unsigned int aw0 = (a0.x ? 0x3F80u : 0u) | ((a0.y ? 0x3F80u : 0u) << 16);
    *reinterpret_cast<unsigned int*>(&A_s[0][aslot]) = aw0;
  }
  int2 aregs = *reinterpret_cast<const int2*>(aptr + BK);           // A(1)
#pragma unroll
  for (int g = 0; g < 2; ++g)
    gld_lds16(evTb + (size_t)(wid * 32 + g * 16 + brow_in) * LK + BK + bsrc_off,
              &B_s[1][(wid * 32 + g * 16) * BK]);                   // B(1)
  __syncthreads();   // full drain once; pipeline fills from here

  unsigned short *Ac = A_s[0], *An1 = A_s[1], *An2 = A_s[2];
  unsigned short *Bc = B_s[0], *Bn1 = B_s[1], *Bn2 = B_s[2];

  f32x4 acc[4] = {};
  f32x4 accd = {};
  const short8v z8 = {};

#pragma unroll 1
  for (int t32 = 0; t32 < 64; ++t32) {
    // ---- issue loads for tile t+2 (wrap at end: lands in dead buffer) ----
    const int k2 = ((t32 + 2) & 63) * BK;
    const int2 anew = *reinterpret_cast<const int2*>(aptr + k2);
#pragma unroll
    for (int g = 0; g < 2; ++g)
      gld_lds16(evTb + (size_t)(wid * 32 + g * 16 + brow_in) * LK + k2 + bsrc_off,
                Bn2 + (wid * 32 + g * 16) * BK);
    __builtin_amdgcn_sched_barrier(0);   // pin loads above the compute phase

    // ---- compute tile t from Ac/Bc ----
    const short8v af = *reinterpret_cast<const short8v*>(&Ac[aoff]);
    if (wn == 0) {                        // denominator: e-column B-frag
      short8v ev = *reinterpret_cast<const short8v*>(&e_s[t32 * BK + kq * 8]);
      ev = (lr == 0) ? ev : z8;
      accd = __builtin_amdgcn_mfma_f32_16x16x32_bf16(af, ev, accd, 0, 0, 0);
    }
#pragma unroll
    for (int n = 0; n < 4; ++n) {
      const short8v bfv = *reinterpret_cast<const short8v*>(&Bc[boff[n]]);
      acc[n] = __builtin_amdgcn_mfma_f32_16x16x32_bf16(af, bfv, acc[n], 0, 0, 0);
    }

    // ---- counted drain: only tile t+1's loads must have landed ----
    __builtin_amdgcn_sched_barrier(0);
    asm volatile("s_waitcnt vmcnt(3)");  // keep this step's 3 VMEM ops in flight
    __builtin_amdgcn_sched_barrier(0);

    // ---- write A(t+1) (regs loaded 1 step ago, HBM slack ~2 steps) ----
    const unsigned int aw = (aregs.x ? 0x3F80u : 0u) | ((aregs.y ? 0x3F80u : 0u) << 16);
    *reinterpret_cast<unsigned int*>(&An1[aslot]) = aw;

    asm volatile("s_waitcnt lgkmcnt(0)");
    __builtin_amdgcn_sched_barrier(0);
    __builtin_amdgcn_s_barrier();
    __builtin_amdgcn_sched_barrier(0);

    // ---- rotate ----
    aregs = anew;
    unsigned short* tp;
    tp = Ac; Ac = An1; An1 = An2; An2 = tp;
    tp = Bc; Bc = Bn1; Bn1 = Bn2; Bn2 = tp;
  }

  // ---- denominator broadcast ----
  if (wn == 0 && lr == 0) {
#pragma unroll
    for (int r = 0; r < 4; ++r)
      denom_s[wm * 16 + (lane >> 4) * 4 + r] = accd[r];
  }
  __syncthreads();

  // ---- epilogue: divide and store (C layout: col=lane&15, row=(lane>>4)*4+r) --
  const int row0 = wm * 16 + (lane >> 4) * 4;
  float inv[4];
#pragma unroll
  for (int r = 0; r < 4; ++r) {
    const float dn = denom_s[row0 + r];
    inv[r] = (dn != 0.f) ? 1.f / dn : 0.f;   // all-masked row: avoid NaN
  }
#pragma unroll
  for (int n = 0; n < 4; ++n) {
    const int col = wn * 64 + n * 16 + lr;
#pragma unroll
    for (int r = 0; r < 4; ++r)
      out[((size_t)b * LQ + (i0 + row0 + r)) * DD + col] = acc[n][r] * inv[r];
  }
}

extern "C" void kernel_launch(void* const* d_in, const int* in_sizes, int n_in,
                              void* d_out, int out_size, void* d_ws, size_t ws_size,
                              hipStream_t stream) {
  // inputs: 0=query (unused: softmax shift-invariance), 1=key, 2=value, 3=mask, 4=w_align
  const float* key   = (const float*)d_in[1];
  const float* value = (const float*)d_in[2];
  const int*   mask  = (const int*)d_in[3];
  const float* w     = (const float*)d_in[4];
  float* out = (float*)d_out;

  unsigned short* evT = (unsigned short*)d_ws;                              // 8 MB
  unsigned short* eb  = (unsigned short*)((char*)d_ws + (size_t)NB * DD * LK * 2);

  bah_precompute<<<NB * (LK / 64), 256, 0, stream>>>(key, value, w, evT, eb);
  bah_gemm<<<NB * (LQ / 32), 512, 0, stream>>>(mask, evT, eb, out);
}

// Round 5
// 55.073 us; speedup vs baseline: 1.2196x; 1.2196x over previous
//
#include <hip/hip_runtime.h>
#include <hip/hip_bf16.h>

// B=8, Lq=2048, Lk=2048, D=256. out = softmax(mask? sq_i+sk_j : -1e9) @ V.
// sq cancels in softmax => out[i] = (mask[i]·(e*V)) / (mask[i]·e), e=exp(K·w).
// Stage 1: eb (bf16) + evB: PRE-FRAGMENTED B operand — evB[b][ks][n][lane] holds
//   the exact 16B MFMA B-fragment bytes (ks=32-k slice, n=16-d tile) so the GEMM
//   loads B fully coalesced, straight to VGPRs, no LDS, no transpose.
// Stage 2: block = 32 rows x 256 d, 4 waves (wave = 64 d), BK=64. Mask staged
//   bf16 into a 4-deep LDS ring (4KB/tile, XOR-swizzled, conflict-free), 2-step
//   register prefetch; per-step sync = lgkmcnt(0)+s_barrier ONLY — global loads
//   flow across barriers under compiler-counted vmcnt (never drained).
// Denominator folded into MFMA via e-column B-frag (wave 0). 2 blocks/CU.
// Workspace: evB 8 MB + eb 32 KB (same footprint as prior rounds).

#define NB 8
#define LQ 2048
#define LK 2048
#define DD 256

typedef __attribute__((ext_vector_type(8))) short short8v;
typedef __attribute__((ext_vector_type(8))) unsigned short ushort8v;
typedef __attribute__((ext_vector_type(4))) float f32x4;

__device__ inline unsigned short f2bf(float x) {
  union { __hip_bfloat16 h; unsigned short u; } cv;
  cv.h = __float2bfloat16(x);
  return cv.u;
}

__device__ inline uint4 pack_mask8(const int4 a, const int4 b) {
  uint4 p;
  p.x = (a.x ? 0x3F80u : 0u) | (a.y ? 0x3F800000u : 0u);
  p.y = (a.z ? 0x3F80u : 0u) | (a.w ? 0x3F800000u : 0u);
  p.z = (b.x ? 0x3F80u : 0u) | (b.y ? 0x3F800000u : 0u);
  p.w = (b.z ? 0x3F80u : 0u) | (b.w ? 0x3F800000u : 0u);
  return p;
}

// ---------------- Stage 1: eb = bf16(exp(K·w)); evB = pre-fragmented e*V ------
// grid 8*64=512 (b = blk&7 -> XCD), 256 thr. Block owns batch b, 32 j-rows (ks).
__global__ __launch_bounds__(256) void bah_precompute(
    const float* __restrict__ key, const float* __restrict__ value,
    const float* __restrict__ w, unsigned short* __restrict__ evB,
    unsigned short* __restrict__ eb)
{
  __shared__ float e_s[32];
  __shared__ unsigned short t_s[32][260];   // padded: conflict-free transpose

  const int t = threadIdx.x;
  const int lane = t & 63;
  const int wid = t >> 6;                   // 0..3
  const int blk = blockIdx.x;
  const int b = blk & 7;
  const int ks = blk >> 3;                  // 0..63 (32-k slice)
  const int j0 = ks * 32;

  const float4 wv4 = reinterpret_cast<const float4*>(w)[lane];

  // e = exp(K·w): wave wid handles rows 8*wid..8*wid+7
#pragma unroll
  for (int r8 = 0; r8 < 8; ++r8) {
    const int r = wid * 8 + r8;
    const size_t row = (size_t)b * LK + j0 + r;
    const float4 kv = reinterpret_cast<const float4*>(key + row * DD)[lane];
    float s = kv.x * wv4.x + kv.y * wv4.y + kv.z * wv4.z + kv.w * wv4.w;
#pragma unroll
    for (int off = 32; off; off >>= 1) s += __shfl_xor(s, off);
    const float e = __expf(s);              // |K·w| small: no max-shift needed
    if (lane == 0) { e_s[r] = e; eb[row] = f2bf(e); }
  }
  __syncthreads();

  // e*V -> bf16 into padded LDS tile [j][d]
#pragma unroll
  for (int g = 0; g < 8; ++g) {
    const int jr = g * 4 + wid;
    const int d0 = lane * 4;
    const size_t row = (size_t)b * LK + j0 + jr;
    const float4 vv = reinterpret_cast<const float4*>(value + row * DD)[lane];
    const float e = e_s[jr];
    ushort4 u;
    u.x = f2bf(e * vv.x);
    u.y = f2bf(e * vv.y);
    u.z = f2bf(e * vv.z);
    u.w = f2bf(e * vv.w);
    *reinterpret_cast<ushort4*>(&t_s[jr][d0]) = u;
  }
  __syncthreads();

  // fragment gather + coalesced store: wave wid -> n-tiles 4*wid..4*wid+3.
  // Frag def (16x16x32 B-op): lane holds B[k=8*(lane>>4)+i][d=n*16+(lane&15)].
  const int lr = lane & 15;
  const int lj = lane >> 4;
#pragma unroll
  for (int n4 = 0; n4 < 4; ++n4) {
    const int n = wid * 4 + n4;
    ushort8v va;
#pragma unroll
    for (int i = 0; i < 8; ++i) va[i] = t_s[lj * 8 + i][n * 16 + lr];
    *reinterpret_cast<ushort8v*>(
        evB + ((size_t)((b * 64 + ks) * 16 + n) * 64 + lane) * 8) = va;
  }
}

// ---------------- Stage 2: pipelined masked GEMM, barrier guards LDS only -----
// grid 8*64=512 (b = blk&7 -> XCD, evB L2-resident), 256 thr = 4 waves.
// Block tile 32 rows x 256 d; wave wq owns d = [64*wq, 64*wq+64).
__global__ __launch_bounds__(256, 2) void bah_gemm(
    const int* __restrict__ mask, const unsigned short* __restrict__ evB,
    const unsigned short* __restrict__ eb, float* __restrict__ out)
{
  __shared__ unsigned short A_s[4][32 * 64];  // 4-deep ring of bf16 mask tiles
  __shared__ float denom_s[32];

  const int t = threadIdx.x;
  const int lane = t & 63;
  const int wq = t >> 6;                    // 0..3: d quarter
  const int lr = lane & 15;
  const int lj = lane >> 4;

  const int blk = blockIdx.x;
  const int b = blk & 7;
  const int i0 = (blk >> 3) * 32;

  // A staging: wave stages rows 8*wq..8*wq+7; lane -> row rw, 32B contiguous.
  const int rw = wq * 8 + (lane & 7);
  const int cw = lane >> 3;                 // 8-bf16 chunk 0..7
  const int* amask = mask + ((size_t)b * LQ + i0 + rw) * LK + cw * 8;
  const int awr = rw * 64 + ((cw ^ (rw & 7)) * 8);   // swizzled ushort slot

  // B fragment pointers (pre-fragged evB): + ks*8192 ushorts per 32-k slice
  const unsigned short* bB[4];
#pragma unroll
  for (int n = 0; n < 4; ++n)
    bB[n] = evB + ((size_t)(b * 1024 + (4 * wq + n)) * 64 + lane) * 8;
  const unsigned short* ebb = eb + b * 2048 + lj * 8;

  // A frag read offsets: row ra, k-half h -> chunk (4h+lj) ^ (ra&7)
  const int af00 = lr * 64 + (((0 + lj) ^ (lr & 7)) * 8);
  const int af01 = lr * 64 + (((4 + lj) ^ (lr & 7)) * 8);
  const int af10 = (16 + lr) * 64 + (((0 + lj) ^ ((16 + lr) & 7)) * 8);
  const int af11 = (16 + lr) * 64 + (((4 + lj) ^ ((16 + lr) & 7)) * 8);

  f32x4 acc[2][4] = {};
  f32x4 accd0 = {}, accd1 = {};
  const short8v z8 = {};

  // ---- prologue: A(0) -> buf0; A(1) -> regs ----
  {
    const int4 p0 = *reinterpret_cast<const int4*>(amask + 0);
    const int4 p1 = *reinterpret_cast<const int4*>(amask + 4);
    *reinterpret_cast<uint4*>(&A_s[0][awr]) = pack_mask8(p0, p1);
  }
  int4 aC0 = *reinterpret_cast<const int4*>(amask + 64);
  int4 aC1 = *reinterpret_cast<const int4*>(amask + 68);
  __syncthreads();

#pragma unroll 4
  for (int tt = 0; tt < 32; ++tt) {
    const int bufC = tt & 3;
    const int bufW = (tt + 1) & 3;

    // ---- issue all global loads (flow across the barrier via counted vmcnt) --
    short8v bf0[4], bf1[4];
#pragma unroll
    for (int n = 0; n < 4; ++n) {
      bf0[n] = *reinterpret_cast<const short8v*>(bB[n] + (size_t)(2 * tt + 0) * 8192);
      bf1[n] = *reinterpret_cast<const short8v*>(bB[n] + (size_t)(2 * tt + 1) * 8192);
    }
    short8v ef0 = z8, ef1 = z8;
    if (wq == 0) {
      const short8v e0 = *reinterpret_cast<const short8v*>(ebb + (2 * tt + 0) * 32);
      const short8v e1 = *reinterpret_cast<const short8v*>(ebb + (2 * tt + 1) * 32);
      ef0 = (lr == 0) ? e0 : z8;
      ef1 = (lr == 0) ? e1 : z8;
    }
    const int k2 = ((tt + 2) & 31) * 64;    // wrap at end: lands in dead buffer
    const int4 aN0 = *reinterpret_cast<const int4*>(amask + k2);
    const int4 aN1 = *reinterpret_cast<const int4*>(amask + k2 + 4);
    __builtin_amdgcn_sched_barrier(0);

    // ---- write A(t+1) (regs from last step), certify with lgkm+barrier only --
    *reinterpret_cast<uint4*>(&A_s[bufW][awr]) = pack_mask8(aC0, aC1);
    asm volatile("s_waitcnt lgkmcnt(0)" ::: "memory");
    __builtin_amdgcn_sched_barrier(0);
    __builtin_amdgcn_s_barrier();
    __builtin_amdgcn_sched_barrier(0);

    // ---- compute tile t ----
#pragma unroll
    for (int h = 0; h < 2; ++h) {
      const short8v a0 = *reinterpret_cast<const short8v*>(&A_s[bufC][h ? af01 : af00]);
      const short8v a1 = *reinterpret_cast<const short8v*>(&A_s[bufC][h ? af11 : af10]);
      if (wq == 0) {
        const short8v efh = h ? ef1 : ef0;
        accd0 = __builtin_amdgcn_mfma_f32_16x16x32_bf16(a0, efh, accd0, 0, 0, 0);
        accd1 = __builtin_amdgcn_mfma_f32_16x16x32_bf16(a1, efh, accd1, 0, 0, 0);
      }
#pragma unroll
      for (int n = 0; n < 4; ++n) {
        const short8v bv = h ? bf1[n] : bf0[n];
        acc[0][n] = __builtin_amdgcn_mfma_f32_16x16x32_bf16(a0, bv, acc[0][n], 0, 0, 0);
        acc[1][n] = __builtin_amdgcn_mfma_f32_16x16x32_bf16(a1, bv, acc[1][n], 0, 0, 0);
      }
    }
    aC0 = aN0; aC1 = aN1;
  }

  // ---- denominator broadcast (C col 0 lives in lanes with lr==0) ----
  if (wq == 0 && lr == 0) {
#pragma unroll
    for (int r = 0; r < 4; ++r) {
      denom_s[lj * 4 + r] = accd0[r];
      denom_s[16 + lj * 4 + r] = accd1[r];
    }
  }
  __syncthreads();

  // ---- epilogue: divide and store (C layout: col=lane&15, row=lj*4+r) ----
#pragma unroll
  for (int m = 0; m < 2; ++m) {
    const int row0 = m * 16 + lj * 4;
    float inv[4];
#pragma unroll
    for (int r = 0; r < 4; ++r) {
      const float dn = denom_s[row0 + r];
      inv[r] = (dn != 0.f) ? 1.f / dn : 0.f;   // all-masked row: avoid NaN
    }
#pragma unroll
    for (int n = 0; n < 4; ++n) {
      const int col = wq * 64 + n * 16 + lr;
#pragma unroll
      for (int r = 0; r < 4; ++r)
        out[((size_t)b * LQ + (i0 + row0 + r)) * DD + col] = acc[m][n][r] * inv[r];
    }
  }
}

extern "C" void kernel_launch(void* const* d_in, const int* in_sizes, int n_in,
                              void* d_out, int out_size, void* d_ws, size_t ws_size,
                              hipStream_t stream) {
  // inputs: 0=query (unused: softmax shift-invariance), 1=key, 2=value, 3=mask, 4=w_align
  const float* key   = (const float*)d_in[1];
  const float* value = (const float*)d_in[2];
  const int*   mask  = (const int*)d_in[3];
  const float* w     = (const float*)d_in[4];
  float* out = (float*)d_out;

  unsigned short* evB = (unsigned short*)d_ws;                              // 8 MB
  unsigned short* eb  = (unsigned short*)((char*)d_ws + (size_t)NB * DD * LK * 2);

  bah_precompute<<<NB * (LK / 32), 256, 0, stream>>>(key, value, w, evB, eb);
  bah_gemm<<<NB * (LQ / 32), 256, 0, stream>>>(mask, evB, eb, out);
}

// Round 6
// 54.140 us; speedup vs baseline: 1.2407x; 1.0172x over previous
//
#include <hip/hip_runtime.h>
#include <hip/hip_bf16.h>

// B=8, Lq=2048, Lk=2048, D=256. out = softmax(mask? sq_i+sk_j : -1e9) @ V.
// sq cancels in softmax => out[i] = (mask[i]·(e*V)) / (mask[i]·e), e=exp(K·w).
// Stage 1: eb (bf16) + evB: PRE-FRAGMENTED B operand — evB[b][ks][n][lane] holds
//   the exact 16B MFMA B-fragment bytes so the GEMM loads B fully coalesced.
// Stage 2: block = 32 rows x 256 d, 4 waves, BK=64. Mask staged bf16 into a
//   4-deep LDS ring (2-step reg prefetch); B/e fragments REGISTER-PREFETCHED
//   one step ahead (double-buffered, unroll-2 => static indices). Per-step
//   sync = lgkmcnt(0)+s_barrier only; global loads cross barriers under
//   compiler-counted vmcnt (never drained). Denominator folded into MFMA via
//   e-column B-frag (wave 0). 2 blocks/CU.
// Workspace: evB 8 MB + eb 32 KB.

#define NB 8
#define LQ 2048
#define LK 2048
#define DD 256

typedef __attribute__((ext_vector_type(8))) short short8v;
typedef __attribute__((ext_vector_type(8))) unsigned short ushort8v;
typedef __attribute__((ext_vector_type(4))) float f32x4;

__device__ inline unsigned short f2bf(float x) {
  union { __hip_bfloat16 h; unsigned short u; } cv;
  cv.h = __float2bfloat16(x);
  return cv.u;
}

__device__ inline uint4 pack_mask8(const int4 a, const int4 b) {
  uint4 p;
  p.x = (a.x ? 0x3F80u : 0u) | (a.y ? 0x3F800000u : 0u);
  p.y = (a.z ? 0x3F80u : 0u) | (a.w ? 0x3F800000u : 0u);
  p.z = (b.x ? 0x3F80u : 0u) | (b.y ? 0x3F800000u : 0u);
  p.w = (b.z ? 0x3F80u : 0u) | (b.w ? 0x3F800000u : 0u);
  return p;
}

// ---------------- Stage 1: eb = bf16(exp(K·w)); evB = pre-fragmented e*V ------
// grid 8*64=512 (b = blk&7 -> XCD), 256 thr. Block owns batch b, 32 j-rows (ks).
__global__ __launch_bounds__(256) void bah_precompute(
    const float* __restrict__ key, const float* __restrict__ value,
    const float* __restrict__ w, unsigned short* __restrict__ evB,
    unsigned short* __restrict__ eb)
{
  __shared__ float e_s[32];
  __shared__ unsigned short t_s[32][260];   // padded: conflict-free transpose

  const int t = threadIdx.x;
  const int lane = t & 63;
  const int wid = t >> 6;                   // 0..3
  const int blk = blockIdx.x;
  const int b = blk & 7;
  const int ks = blk >> 3;                  // 0..63 (32-k slice)
  const int j0 = ks * 32;

  const float4 wv4 = reinterpret_cast<const float4*>(w)[lane];

  // e = exp(K·w): wave wid handles rows 8*wid..8*wid+7
#pragma unroll
  for (int r8 = 0; r8 < 8; ++r8) {
    const int r = wid * 8 + r8;
    const size_t row = (size_t)b * LK + j0 + r;
    const float4 kv = reinterpret_cast<const float4*>(key + row * DD)[lane];
    float s = kv.x * wv4.x + kv.y * wv4.y + kv.z * wv4.z + kv.w * wv4.w;
#pragma unroll
    for (int off = 32; off; off >>= 1) s += __shfl_xor(s, off);
    const float e = __expf(s);              // |K·w| small: no max-shift needed
    if (lane == 0) { e_s[r] = e; eb[row] = f2bf(e); }
  }
  __syncthreads();

  // e*V -> bf16 into padded LDS tile [j][d]
#pragma unroll
  for (int g = 0; g < 8; ++g) {
    const int jr = g * 4 + wid;
    const int d0 = lane * 4;
    const size_t row = (size_t)b * LK + j0 + jr;
    const float4 vv = reinterpret_cast<const float4*>(value + row * DD)[lane];
    const float e = e_s[jr];
    ushort4 u;
    u.x = f2bf(e * vv.x);
    u.y = f2bf(e * vv.y);
    u.z = f2bf(e * vv.z);
    u.w = f2bf(e * vv.w);
    *reinterpret_cast<ushort4*>(&t_s[jr][d0]) = u;
  }
  __syncthreads();

  // fragment gather + coalesced store: wave wid -> n-tiles 4*wid..4*wid+3.
  // Frag def (16x16x32 B-op): lane holds B[k=8*(lane>>4)+i][d=n*16+(lane&15)].
  const int lr = lane & 15;
  const int lj = lane >> 4;
#pragma unroll
  for (int n4 = 0; n4 < 4; ++n4) {
    const int n = wid * 4 + n4;
    ushort8v va;
#pragma unroll
    for (int i = 0; i < 8; ++i) va[i] = t_s[lj * 8 + i][n * 16 + lr];
    *reinterpret_cast<ushort8v*>(
        evB + ((size_t)((b * 64 + ks) * 16 + n) * 64 + lane) * 8) = va;
  }
}

// ---------------- Stage 2: pipelined masked GEMM, all loads >=1 step ahead ----
// grid 8*64=512 (b = blk&7 -> XCD, evB L2-resident), 256 thr = 4 waves.
// Block tile 32 rows x 256 d; wave wq owns d = [64*wq, 64*wq+64).
__global__ __launch_bounds__(256, 2) void bah_gemm(
    const int* __restrict__ mask, const unsigned short* __restrict__ evB,
    const unsigned short* __restrict__ eb, float* __restrict__ out)
{
  __shared__ unsigned short A_s[4][32 * 64];  // 4-deep ring of bf16 mask tiles
  __shared__ float denom_s[32];

  const int t = threadIdx.x;
  const int lane = t & 63;
  const int wq = t >> 6;                    // 0..3: d quarter
  const int lr = lane & 15;
  const int lj = lane >> 4;

  const int blk = blockIdx.x;
  const int b = blk & 7;
  const int i0 = (blk >> 3) * 32;

  // A staging: wave stages rows 8*wq..8*wq+7; lane -> row rw, 32B contiguous.
  const int rw = wq * 8 + (lane & 7);
  const int cw = lane >> 3;                 // 8-bf16 chunk 0..7
  const int* amask = mask + ((size_t)b * LQ + i0 + rw) * LK + cw * 8;
  const int awr = rw * 64 + ((cw ^ (rw & 7)) * 8);   // swizzled ushort slot

  // B fragment pointers (pre-fragged evB): + ks*8192 ushorts per 32-k slice
  const unsigned short* bB[4];
#pragma unroll
  for (int n = 0; n < 4; ++n)
    bB[n] = evB + ((size_t)(b * 1024 + (4 * wq + n)) * 64 + lane) * 8;
  const unsigned short* ebb = eb + b * 2048 + lj * 8;

  // A frag read offsets: row ra, k-half h -> chunk (4h+lj) ^ (ra&7)
  const int af00 = lr * 64 + (((0 + lj) ^ (lr & 7)) * 8);
  const int af01 = lr * 64 + (((4 + lj) ^ (lr & 7)) * 8);
  const int af10 = (16 + lr) * 64 + (((0 + lj) ^ ((16 + lr) & 7)) * 8);
  const int af11 = (16 + lr) * 64 + (((4 + lj) ^ ((16 + lr) & 7)) * 8);

  f32x4 acc[2][4] = {};
  f32x4 accd0 = {}, accd1 = {};
  const short8v z8 = {};

  // ---- register-prefetch state: [buf][h][n], static-indexed via unroll-2 ----
  short8v bfr[2][2][4];
  short8v efr[2][2];

  // ---- prologue: A(0) -> buf0; A(1) -> regs; B(0)/e(0) -> reg buf0 ----
  {
    const int4 p0 = *reinterpret_cast<const int4*>(amask + 0);
    const int4 p1 = *reinterpret_cast<const int4*>(amask + 4);
    *reinterpret_cast<uint4*>(&A_s[0][awr]) = pack_mask8(p0, p1);
  }
  int4 aC0 = *reinterpret_cast<const int4*>(amask + 64);
  int4 aC1 = *reinterpret_cast<const int4*>(amask + 68);
#pragma unroll
  for (int n = 0; n < 4; ++n) {
    bfr[0][0][n] = *reinterpret_cast<const short8v*>(bB[n] + (size_t)0 * 8192);
    bfr[0][1][n] = *reinterpret_cast<const short8v*>(bB[n] + (size_t)1 * 8192);
  }
  efr[0][0] = z8; efr[0][1] = z8;
  if (wq == 0 && lr == 0) {
    efr[0][0] = *reinterpret_cast<const short8v*>(ebb + 0 * 32);
    efr[0][1] = *reinterpret_cast<const short8v*>(ebb + 1 * 32);
  }
  __syncthreads();

#pragma unroll 2
  for (int tt = 0; tt < 32; ++tt) {
    const int cur = tt & 1;
    const int nxt = cur ^ 1;
    const int bufC = tt & 3;
    const int bufW = (tt + 1) & 3;

    // ---- issue next-step loads (cross the barrier via counted vmcnt) ----
    const int ksn = ((tt + 1) & 31) * 2;    // wrap at end: dead loads
#pragma unroll
    for (int n = 0; n < 4; ++n) {
      bfr[nxt][0][n] = *reinterpret_cast<const short8v*>(bB[n] + (size_t)(ksn + 0) * 8192);
      bfr[nxt][1][n] = *reinterpret_cast<const short8v*>(bB[n] + (size_t)(ksn + 1) * 8192);
    }
    efr[nxt][0] = z8; efr[nxt][1] = z8;
    if (wq == 0 && lr == 0) {
      efr[nxt][0] = *reinterpret_cast<const short8v*>(ebb + (ksn + 0) * 32);
      efr[nxt][1] = *reinterpret_cast<const short8v*>(ebb + (ksn + 1) * 32);
    }
    const int k2 = ((tt + 2) & 31) * 64;
    const int4 aN0 = *reinterpret_cast<const int4*>(amask + k2);
    const int4 aN1 = *reinterpret_cast<const int4*>(amask + k2 + 4);
    __builtin_amdgcn_sched_barrier(0);

    // ---- write A(t+1) (regs from last step), certify with lgkm+barrier only --
    *reinterpret_cast<uint4*>(&A_s[bufW][awr]) = pack_mask8(aC0, aC1);
    asm volatile("s_waitcnt lgkmcnt(0)" ::: "memory");
    __builtin_amdgcn_sched_barrier(0);
    __builtin_amdgcn_s_barrier();
    __builtin_amdgcn_sched_barrier(0);

    // ---- compute tile t entirely from regs + LDS-A ----
#pragma unroll
    for (int h = 0; h < 2; ++h) {
      const short8v a0 = *reinterpret_cast<const short8v*>(&A_s[bufC][h ? af01 : af00]);
      const short8v a1 = *reinterpret_cast<const short8v*>(&A_s[bufC][h ? af11 : af10]);
      if (wq == 0) {
        accd0 = __builtin_amdgcn_mfma_f32_16x16x32_bf16(a0, efr[cur][h], accd0, 0, 0, 0);
        accd1 = __builtin_amdgcn_mfma_f32_16x16x32_bf16(a1, efr[cur][h], accd1, 0, 0, 0);
      }
#pragma unroll
      for (int n = 0; n < 4; ++n) {
        acc[0][n] = __builtin_amdgcn_mfma_f32_16x16x32_bf16(a0, bfr[cur][h][n], acc[0][n], 0, 0, 0);
        acc[1][n] = __builtin_amdgcn_mfma_f32_16x16x32_bf16(a1, bfr[cur][h][n], acc[1][n], 0, 0, 0);
      }
    }
    aC0 = aN0; aC1 = aN1;
  }

  // ---- denominator broadcast (C col 0 lives in lanes with lr==0) ----
  if (wq == 0 && lr == 0) {
#pragma unroll
    for (int r = 0; r < 4; ++r) {
      denom_s[lj * 4 + r] = accd0[r];
      denom_s[16 + lj * 4 + r] = accd1[r];
    }
  }
  __syncthreads();

  // ---- epilogue: divide and store (C layout: col=lane&15, row=lj*4+r) ----
#pragma unroll
  for (int m = 0; m < 2; ++m) {
    const int row0 = m * 16 + lj * 4;
    float inv[4];
#pragma unroll
    for (int r = 0; r < 4; ++r) {
      const float dn = denom_s[row0 + r];
      inv[r] = (dn != 0.f) ? 1.f / dn : 0.f;   // all-masked row: avoid NaN
    }
#pragma unroll
    for (int n = 0; n < 4; ++n) {
      const int col = wq * 64 + n * 16 + lr;
#pragma unroll
      for (int r = 0; r < 4; ++r)
        out[((size_t)b * LQ + (i0 + row0 + r)) * DD + col] = acc[m][n][r] * inv[r];
    }
  }
}

extern "C" void kernel_launch(void* const* d_in, const int* in_sizes, int n_in,
                              void* d_out, int out_size, void* d_ws, size_t ws_size,
                              hipStream_t stream) {
  // inputs: 0=query (unused: softmax shift-invariance), 1=key, 2=value, 3=mask, 4=w_align
  const float* key   = (const float*)d_in[1];
  const float* value = (const float*)d_in[2];
  const int*   mask  = (const int*)d_in[3];
  const float* w     = (const float*)d_in[4];
  float* out = (float*)d_out;

  unsigned short* evB = (unsigned short*)d_ws;                              // 8 MB
  unsigned short* eb  = (unsigned short*)((char*)d_ws + (size_t)NB * DD * LK * 2);

  bah_precompute<<<NB * (LK / 32), 256, 0, stream>>>(key, value, w, evB, eb);
  bah_gemm<<<NB * (LQ / 32), 256, 0, stream>>>(mask, evB, eb, out);
}